// Round 3
// baseline (135.102 us; speedup 1.0000x reference)
//
#include <hip/hip_runtime.h>

// DecoupledSOLOHead: SOLO mask decode + Matrix NMS (gaussian), MI355X/gfx950.
//
// R3 changes vs R2 (passed, 131.3 us; top-5 dispatches are all harness 268MB
// ws-poison fills @ ~43 us — our kernels each < 41 us):
//  - maskgen inverted: block = 64-px tile, stages all 128 x-rows + 128 y-rows
//    into LDS (row stride 65 to scatter banks), thread = det. Global traffic
//    drops 243 MB logical -> 62 MB (each seg element read exactly once).
//  - per-lane stats + per-lane u64 bit build (constant shifts, full unroll);
//    partials [tile][det] written coalesced; finalize reduces 950 partials.
//  - bit layout = pixel-order per 64-px tile (a fixed permutation vs R2 —
//    AND+popcount invariant). NWORDS 952 -> 950, NW2 -> 475.

#define N_DET 500
#define HW    (200 * 304)        // 60800
#define TILE  64
#define NT    (HW / TILE)        // 950 tiles, exact
#define NWORDS NT                // one u64 word per det per tile
#define NW2   (NWORDS / 2)       // 475 ulonglong2 granules
#define LSTR  65                 // LDS row stride (floats): banks (xi+px)%32
#define MASK_THR 0.005f
#define SIGMA 2.0f

// ---------------- Kernel A: pixel-tiled broadcast decode + bit-pack ------------
__global__ __launch_bounds__(512) void maskgen_kernel(
    const float* __restrict__ seg_x, const float* __restrict__ seg_y,
    const int* __restrict__ x_inds, const int* __restrict__ y_inds,
    unsigned long long* __restrict__ packed,   // [N_DET][NWORDS] det-major
    float* __restrict__ part_sum,              // [NT][N_DET]
    int*   __restrict__ part_cnt)              // [NT][N_DET]
{
    __shared__ float sx[128 * LSTR];           // 33,280 B
    __shared__ float sy[128 * LSTR];           // 33,280 B
    const int t   = blockIdx.x;
    const int tid = threadIdx.x;
    const int base_g = t * TILE;

    // stage 128 rows x 64 px of each operand; float4 global loads (each element
    // read exactly once across the whole grid), scalar LDS stores (padded rows)
    for (int e = tid; e < 128 * 16; e += 512) {
        const int r  = e >> 4;                 // row 0..127
        const int c4 = (e & 15) << 2;          // px 0..60 step 4
        const float4 vx = *(const float4*)(seg_x + (size_t)r * HW + base_g + c4);
        const float4 vy = *(const float4*)(seg_y + (size_t)r * HW + base_g + c4);
        float* dx = sx + r * LSTR + c4;
        float* dy = sy + r * LSTR + c4;
        dx[0] = vx.x; dx[1] = vx.y; dx[2] = vx.z; dx[3] = vx.w;
        dy[0] = vy.x; dy[1] = vy.y; dy[2] = vy.z; dy[3] = vy.w;
    }
    __syncthreads();

    const int n = tid;                         // one det per thread
    if (n < N_DET) {
        const float* __restrict__ rx = sx + x_inds[n] * LSTR;
        const float* __restrict__ ry = sy + y_inds[n] * LSTR;
        float ssum = 0.0f;
        int   cnt  = 0;
        unsigned int lo = 0u, hi = 0u;
        #pragma unroll
        for (int p = 0; p < 32; ++p) {
            const float v = rx[p] * ry[p];
            if (v > MASK_THR) { ssum += v; ++cnt; lo |= (1u << p); }
        }
        #pragma unroll
        for (int p = 0; p < 32; ++p) {
            const float v = rx[32 + p] * ry[32 + p];
            if (v > MASK_THR) { ssum += v; ++cnt; hi |= (1u << p); }
        }
        packed[(size_t)n * NWORDS + t] = ((unsigned long long)hi << 32) | lo;
        part_sum[(size_t)t * N_DET + n] = ssum;   // coalesced
        part_cnt[(size_t)t * N_DET + n] = cnt;    // coalesced
    }
}

// ---------------- Kernel A2: reduce 950 tile-partials -> sum_masks, scores -----
__global__ __launch_bounds__(64) void finalize_kernel(
    const float* __restrict__ part_sum, const int* __restrict__ part_cnt,
    const float* __restrict__ cate_scores,
    float* __restrict__ sum_masks, float* __restrict__ scores)
{
    const int n    = blockIdx.x;
    const int lane = threadIdx.x;
    float S = 0.0f; int C = 0;
    for (int t = lane; t < NT; t += 64) {
        S += part_sum[(size_t)t * N_DET + n];
        C += part_cnt[(size_t)t * N_DET + n];
    }
    #pragma unroll
    for (int off = 32; off; off >>= 1) {
        S += __shfl_down(S, off);
        C += __shfl_down(C, off);
    }
    if (lane == 0) {
        const float sm = (float)C;
        sum_masks[n] = sm;
        scores[n] = cate_scores[n] * (S / fmaxf(sm, 1.0f));
    }
}

// ---------------- Kernel B: same-class pairwise IoU via popcount ---------------
__global__ __launch_bounds__(256) void pair_iou_kernel(
    const unsigned long long* __restrict__ packed,
    const float* __restrict__ sum_masks,
    const int* __restrict__ labels,
    float* __restrict__ d2col,    // [N][N] col-major: d2col[j*N+i] = decay_iou^2
    float* __restrict__ comp2)    // [N] comp_iou^2
{
    const int j   = blockIdx.x;
    const int tid = threadIdx.x;
    const int lane = tid & 63, wav = tid >> 6;

    __shared__ int   s_lab[N_DET];
    __shared__ float s_sm[N_DET];
    __shared__ int   s_list[N_DET];
    __shared__ int   s_cnt;
    __shared__ float s_max[4];

    if (tid == 0) s_cnt = 0;
    for (int i = tid; i < N_DET; i += 256) {
        s_lab[i] = labels[i];
        s_sm[i]  = sum_masks[i];
        d2col[(size_t)j * N_DET + i] = 0.0f;   // ws is re-poisoned each launch
    }
    __syncthreads();

    const int   lj = s_lab[j];
    const float sj = s_sm[j];
    for (int i = tid; i < j; i += 256)
        if (s_lab[i] == lj) { const int p = atomicAdd(&s_cnt, 1); s_list[p] = i; }
    __syncthreads();
    const int cnt = s_cnt;

    // preload j's mask fragment into registers (475 ulonglong2 across 64 lanes)
    const ulonglong2* __restrict__ pj2 = (const ulonglong2*)(packed + (size_t)j * NWORDS);
    ulonglong2 bj[8];
    #pragma unroll
    for (int t = 0; t < 8; ++t) {
        const int w = lane + (t << 6);
        if (w < NW2) bj[t] = pj2[w];
        else { bj[t].x = 0ull; bj[t].y = 0ull; }
    }

    float wmax = 0.0f;
    for (int p = wav; p < cnt; p += 4) {       // one wave per pair
        const int i = s_list[p];
        const ulonglong2* __restrict__ pi2 = (const ulonglong2*)(packed + (size_t)i * NWORDS);
        int part = 0;
        #pragma unroll
        for (int t = 0; t < 8; ++t) {
            const int w = lane + (t << 6);
            if (w < NW2) {
                const ulonglong2 a = pi2[w];
                part += __popcll(a.x & bj[t].x) + __popcll(a.y & bj[t].y);
            }
        }
        #pragma unroll
        for (int off = 32; off; off >>= 1) part += __shfl_down(part, off);
        if (lane == 0) {
            const float uni = s_sm[i] + sj - (float)part;
            const float iou = (float)part / fmaxf(uni, 1e-6f);
            d2col[(size_t)j * N_DET + i] = iou * iou;
            wmax = fmaxf(wmax, iou);
        }
    }
    if (lane == 0) s_max[wav] = wmax;
    __syncthreads();
    if (tid == 0) {
        const float c = fmaxf(fmaxf(s_max[0], s_max[1]), fmaxf(s_max[2], s_max[3]));
        comp2[j] = c * c;
    }
}

// ---------------- Kernel C: decay coef + final scores --------------------------
__global__ __launch_bounds__(64) void decay_kernel(
    const float* __restrict__ d2col,
    const float* __restrict__ comp2,
    const float* __restrict__ scores,
    float* __restrict__ out)
{
    const int j = blockIdx.x;
    const int lane = threadIdx.x;
    float m = 1e30f;
    for (int i = lane; i < N_DET; i += 64)
        m = fminf(m, comp2[i] - d2col[(size_t)j * N_DET + i]);
    #pragma unroll
    for (int off = 32; off; off >>= 1)
        m = fminf(m, __shfl_down(m, off));
    if (lane == 0) out[j] = scores[j] * expf(SIGMA * m);
}

extern "C" void kernel_launch(void* const* d_in, const int* in_sizes, int n_in,
                              void* d_out, int out_size, void* d_ws, size_t ws_size,
                              hipStream_t stream) {
    const float* cate_scores = (const float*)d_in[0];
    const float* seg_x       = (const float*)d_in[1];
    const float* seg_y       = (const float*)d_in[2];
    const int*   labels      = (const int*)d_in[3];
    const int*   x_inds      = (const int*)d_in[4];
    const int*   y_inds      = (const int*)d_in[5];
    float* out = (float*)d_out;

    // workspace layout (16B-aligned blocks); total ~8.61 MB
    char* ws = (char*)d_ws;
    unsigned long long* packed = (unsigned long long*)(ws + 0);   // 500*950*8 = 3,800,000
    float* d2col     = (float*)(ws + 3800000);                    // 1,000,000
    float* part_sum  = (float*)(ws + 4800000);                    // 950*500*4 = 1,900,000
    int*   part_cnt  = (int*)  (ws + 6700000);                    // 1,900,000
    float* scores    = (float*)(ws + 8600000);                    // 2,000
    float* comp2     = (float*)(ws + 8602048);                    // 2,000
    float* sum_masks = (float*)(ws + 8604096);                    // 2,000

    maskgen_kernel <<<NT, 512, 0, stream>>>(seg_x, seg_y, x_inds, y_inds,
                                            packed, part_sum, part_cnt);
    finalize_kernel<<<N_DET, 64, 0, stream>>>(part_sum, part_cnt, cate_scores,
                                              sum_masks, scores);
    pair_iou_kernel<<<N_DET, 256, 0, stream>>>(packed, sum_masks, labels, d2col, comp2);
    decay_kernel   <<<N_DET, 64, 0, stream>>>(d2col, comp2, scores, out);
}